// Round 1
// baseline (329.723 us; speedup 1.0000x reference)
//
#include <hip/hip_runtime.h>

// Problem constants
constexpr int BATCH = 32768;
constexpr int KDIM  = 128;    // IN_F
constexpr int NDIM  = 2048;   // OUT_F
constexpr int ROWS  = 8;      // batch rows per block
constexpr int THREADS = 256;

__device__ inline float wave_sum(float v) {
    #pragma unroll
    for (int off = 32; off > 0; off >>= 1) v += __shfl_xor(v, off, 64);
    return v;
}

// Fused: z = (x @ W) * prev_mask ; out = sparsemax(z) per row.
// Block: 256 threads, 8 batch rows. Each thread: 8 rows x 8 cols
// (cols tid*4..tid*4+3 and 1024+tid*4..+3 -> coalesced float4).
// Sparsemax via Michelot fixed-point (exact simplex projection):
//   tau = (sum_active - 1)/|active|; active = {z > tau}; iterate to fixpoint.
__global__ __launch_bounds__(THREADS)
void fused_sparsemax_kernel(const float* __restrict__ x,
                            const float* __restrict__ pm,
                            const float* __restrict__ W,
                            float* __restrict__ out)
{
    __shared__ float xs[ROWS][KDIM];   // 4 KB
    __shared__ float zs[4][NDIM];      // 32 KB (half the rows at a time)

    const int tid  = threadIdx.x;
    const int lane = tid & 63;
    const int wv   = tid >> 6;
    const long r0  = (long)blockIdx.x * ROWS;

    // ---- stage x rows (8 x 128 = 1024 floats = 256 float4, 1 per thread) ----
    {
        const float4* src = reinterpret_cast<const float4*>(x + r0 * KDIM);
        reinterpret_cast<float4*>(&xs[0][0])[tid] = src[tid];
    }
    __syncthreads();

    // ---- GEMM: acc[r][j], j=0..3 -> cols tid*4+j, j=4..7 -> cols 1024+tid*4+(j-4)
    float acc[ROWS][8];
    #pragma unroll
    for (int r = 0; r < ROWS; ++r)
        #pragma unroll
        for (int j = 0; j < 8; ++j) acc[r][j] = 0.f;

    const float4* Wv4 = reinterpret_cast<const float4*>(W);
    #pragma unroll 4
    for (int k = 0; k < KDIM; ++k) {
        const float4 w0 = Wv4[k * (NDIM / 4) + tid];
        const float4 w1 = Wv4[k * (NDIM / 4) + 256 + tid];
        #pragma unroll
        for (int r = 0; r < ROWS; ++r) {
            const float xv = xs[r][k];
            acc[r][0] = fmaf(xv, w0.x, acc[r][0]);
            acc[r][1] = fmaf(xv, w0.y, acc[r][1]);
            acc[r][2] = fmaf(xv, w0.z, acc[r][2]);
            acc[r][3] = fmaf(xv, w0.w, acc[r][3]);
            acc[r][4] = fmaf(xv, w1.x, acc[r][4]);
            acc[r][5] = fmaf(xv, w1.y, acc[r][5]);
            acc[r][6] = fmaf(xv, w1.z, acc[r][6]);
            acc[r][7] = fmaf(xv, w1.w, acc[r][7]);
        }
    }

    const float4* pmv = reinterpret_cast<const float4*>(pm);

    #pragma unroll
    for (int half = 0; half < 2; ++half) {
        __syncthreads();   // zs free (or first use)
        // ---- apply prev_mask gate, scatter z rows into LDS ----
        #pragma unroll
        for (int rr = 0; rr < 4; ++rr) {
            const int r = half * 4 + rr;              // compile-time (both loops unrolled)
            const long rowbase4 = (r0 + r) * (NDIM / 4);
            const float4 m0 = pmv[rowbase4 + tid];
            const float4 m1 = pmv[rowbase4 + 256 + tid];
            float4 z0, z1;
            z0.x = acc[r][0] * m0.x; z0.y = acc[r][1] * m0.y;
            z0.z = acc[r][2] * m0.z; z0.w = acc[r][3] * m0.w;
            z1.x = acc[r][4] * m1.x; z1.y = acc[r][5] * m1.y;
            z1.z = acc[r][6] * m1.z; z1.w = acc[r][7] * m1.w;
            float4* zr = reinterpret_cast<float4*>(&zs[rr][0]);
            zr[tid]       = z0;
            zr[256 + tid] = z1;
        }
        __syncthreads();

        // ---- wave wv owns row (half*4 + wv): 64 lanes x 32 values ----
        float zvv[32];
        const float4* zr = reinterpret_cast<const float4*>(&zs[wv][0]);
        #pragma unroll
        for (int c = 0; c < 8; ++c) {
            const float4 v = zr[c * 64 + lane];
            zvv[c * 4 + 0] = v.x; zvv[c * 4 + 1] = v.y;
            zvv[c * 4 + 2] = v.z; zvv[c * 4 + 3] = v.w;
        }

        // Michelot: tau monotone non-decreasing -> global filter valid.
        float s = 0.f;
        #pragma unroll
        for (int i = 0; i < 32; ++i) s += zvv[i];
        s = wave_sum(s);
        float tau = (s - 1.f) / 2048.f;
        float cprev = 2048.f;
        for (int it = 0; it < 64; ++it) {
            float ps = 0.f, pc = 0.f;
            #pragma unroll
            for (int i = 0; i < 32; ++i) {
                if (zvv[i] > tau) { ps += zvv[i]; pc += 1.f; }
            }
            ps = wave_sum(ps);
            pc = wave_sum(pc);     // small ints, exact in f32
            tau = (ps - 1.f) / pc; // pc >= 1 always (max z > mean-1/n)
            if (pc == cprev) break;   // active set stable -> fixpoint
            cprev = pc;
        }

        // ---- write out = max(z - tau, 0), coalesced float4 ----
        float4* orow = reinterpret_cast<float4*>(out + (r0 + half * 4 + wv) * NDIM);
        #pragma unroll
        for (int c = 0; c < 8; ++c) {
            float4 v;
            v.x = fmaxf(zvv[c * 4 + 0] - tau, 0.f);
            v.y = fmaxf(zvv[c * 4 + 1] - tau, 0.f);
            v.z = fmaxf(zvv[c * 4 + 2] - tau, 0.f);
            v.w = fmaxf(zvv[c * 4 + 3] - tau, 0.f);
            orow[c * 64 + lane] = v;
        }
    }
}

extern "C" void kernel_launch(void* const* d_in, const int* in_sizes, int n_in,
                              void* d_out, int out_size, void* d_ws, size_t ws_size,
                              hipStream_t stream) {
    const float* x  = (const float*)d_in[0];   // [32768, 128]
    const float* pm = (const float*)d_in[1];   // [32768, 2048]
    const float* W  = (const float*)d_in[2];   // [128, 2048]
    float* out = (float*)d_out;                // [32768, 2048]

    dim3 grid(BATCH / ROWS);                   // 4096 blocks
    dim3 block(THREADS);
    fused_sparsemax_kernel<<<grid, block, 0, stream>>>(x, pm, W, out);
}